// Round 14
// baseline (787.363 us; speedup 1.0000x reference)
//
#include <hip/hip_runtime.h>
#include <hip/hip_bf16.h>
#include <cstdint>
#include <cstddef>

#define FDIM   128
#define NBASIS 20
#define NLAYERS 3
#define RCUT   5.0f
#define PI_F   3.14159265358979323846f
#define CHUNK  64
#define TPB    512

typedef __attribute__((ext_vector_type(8))) short bf16x8;
typedef __attribute__((ext_vector_type(4))) float f32x4;
typedef __attribute__((ext_vector_type(2))) float f32x2;

// 1-ulp rcp is fine: result is rounded to bf16 downstream.
__device__ __forceinline__ float silu_f(float x) {
    return x * __builtin_amdgcn_rcpf(1.f + __expf(-x));
}

__device__ __forceinline__ unsigned short f2bf(float x) {
    __hip_bfloat16 h = __float2bfloat16(x);
    unsigned short u;
    __builtin_memcpy(&u, &h, 2);
    return u;
}

// swizzled element index for bf16 LDS tiles with 128-elem rows
__device__ __forceinline__ int swz(int row, int col) {
    return row * FDIM + (col ^ ((row & 7) << 3));
}
// fp32 staging swizzle (4-elem granules)
__device__ __forceinline__ int swz4(int row, int col) {
    return row * FDIM + (col ^ ((row & 7) << 2));
}

// ---------------------------------------------------------------- small utility kernels
__global__ __launch_bounds__(256)
void atom_init_kernel(const int* __restrict__ zc, const float* __restrict__ emb,
                      float* __restrict__ atom, int N)
{
    int t = blockIdx.x * 256 + threadIdx.x;
    if (t >= N * FDIM) return;
    int n = t >> 7, f = t & 127;
    atom[t] = emb[zc[n]*FDIM + f];
}

__global__ __launch_bounds__(256)
void zero4_kernel(float4* __restrict__ p, int n4)
{
    int t = blockIdx.x * 256 + threadIdx.x;
    if (t < n4) p[t] = make_float4(0.f,0.f,0.f,0.f);
}

// ---------------------------------------------------------------- weight pre-pack
// Fragment order: Wpk[m][((r16*4+ks)*64 + lane)*8 + j]
//   = bf16( W[r16*16 + (lane&15)][ks*32 + (lane>>4)*8 + j] )
__global__ __launch_bounds__(256)
void pack_w_kernel(const float* __restrict__ mnpW1, const float* __restrict__ mnpW2,
                   const float* __restrict__ e11,   const float* __restrict__ e12,
                   const float* __restrict__ e21,   const float* __restrict__ e22,
                   const float* __restrict__ updW,
                   unsigned short* __restrict__ wpk)
{
    int t = blockIdx.x * 256 + threadIdx.x;
    if (t >= 21 * 2048) return;
    int m = t >> 11, p = t & 2047;
    int layer = m / 7, kind = m % 7;
    const float* base;
    switch (kind) {
        case 0: base = mnpW1; break;
        case 1: base = mnpW2; break;
        case 2: base = e11;   break;
        case 3: base = e12;   break;
        case 4: base = e21;   break;
        case 5: base = e22;   break;
        default: base = updW; break;
    }
    base += (size_t)layer * FDIM * FDIM;
    int l   = p & 63, fr = p >> 6;
    int r16 = fr >> 2, ks = fr & 3;
    int row = r16*16 + (l & 15);
    int col = ks*32 + (l >> 4)*8;
    const float* src = base + (size_t)row*FDIM + col;
    float4 v0 = *reinterpret_cast<const float4*>(src);
    float4 v1 = *reinterpret_cast<const float4*>(src + 4);
    unsigned short* dst = wpk + (size_t)t * 8;
    ushort4 o0, o1;
    o0.x = f2bf(v0.x); o0.y = f2bf(v0.y); o0.z = f2bf(v0.z); o0.w = f2bf(v0.w);
    o1.x = f2bf(v1.x); o1.y = f2bf(v1.y); o1.z = f2bf(v1.z); o1.w = f2bf(v1.w);
    *reinterpret_cast<ushort4*>(dst)     = o0;
    *reinterpret_cast<ushort4*>(dst + 4) = o1;
}

// ---------------------------------------------------------------- edge sort (by ei0)
__global__ __launch_bounds__(256)
void hist_kernel(const int* __restrict__ ei0, int* __restrict__ hist, int E)
{
    int e = blockIdx.x * 256 + threadIdx.x;
    if (e < E) atomicAdd(&hist[ei0[e]], 1);
}

__global__ __launch_bounds__(1024)
void prefix_kernel(const int* __restrict__ hist, int* __restrict__ off, int N, int E)
{
    __shared__ int buf[1024];
    __shared__ int carry;
    const int tid = threadIdx.x;
    if (tid == 0) carry = 0;
    __syncthreads();
    for (int base = 0; base < N; base += 1024) {
        int i = base + tid;
        int v = (i < N) ? hist[i] : 0;
        buf[tid] = v;
        __syncthreads();
        for (int d = 1; d < 1024; d <<= 1) {
            int t = (tid >= d) ? buf[tid - d] : 0;
            __syncthreads();
            buf[tid] += t;
            __syncthreads();
        }
        if (i < N) off[i] = carry + buf[tid] - v;   // exclusive
        __syncthreads();
        if (tid == 0) carry += buf[1023];
        __syncthreads();
    }
}

__global__ __launch_bounds__(256)
void scatter_kernel(const int* __restrict__ ei0, const int* __restrict__ ei1,
                    const float* __restrict__ disp, int* __restrict__ off,
                    int* __restrict__ se0, int* __restrict__ se1,
                    float* __restrict__ sdisp, int E)
{
    int e = blockIdx.x * 256 + threadIdx.x;
    if (e >= E) return;
    int n = ei0[e];
    int pos = atomicAdd(&off[n], 1);
    se0[pos] = n;
    se1[pos] = ei1[e];
    sdisp[3*pos+0] = disp[3*e+0];
    sdisp[3*pos+1] = disp[3*e+1];
    sdisp[3*pos+2] = disp[3*e+2];
}

// ================================================================ gemm: A from LDS, B from packed global
__device__ __forceinline__ void gemm_g(const unsigned short* __restrict__ Ab,
                                       const unsigned short* __restrict__ Bpk,
                                       int mr0, int nc0, int lane, f32x4 acc[4])
{
    #pragma unroll
    for (int ks = 0; ks < 4; ++ks) {
        bf16x8 a = *reinterpret_cast<const bf16x8*>(
            &Ab[swz(mr0 + (lane & 15), ks*32 + (lane >> 4)*8)]);
        #pragma unroll
        for (int n = 0; n < 4; ++n) {
            int r16 = (nc0 >> 4) + n;
            bf16x8 b = *reinterpret_cast<const bf16x8*>(
                &Bpk[(size_t)(((r16*4 + ks)*64 + lane)) * 8]);
            acc[n] = __builtin_amdgcn_mfma_f32_16x16x32_bf16(a, b, acc[n], 0, 0, 0);
        }
    }
}

// ================================================================ node MLP (bf16 MFMA, global B)
__global__ __launch_bounds__(TPB, 6)
void node_mlp_g_kernel(const float* __restrict__ in, float* __restrict__ out,
                       const unsigned short* __restrict__ W1pk, const float* __restrict__ b1,
                       const unsigned short* __restrict__ W2pk, const float* __restrict__ b2,
                       int R)
{
    __shared__ __align__(16) unsigned short Ab[CHUNK*FDIM];
    __shared__ __align__(16) unsigned short Hb[CHUNK*FDIM];
    const int tid  = threadIdx.x;
    const int lane = tid & 63;
    const int wid  = tid >> 6;
    const int r0   = blockIdx.x * CHUNK;
    const int mr0  = (wid & 3) * 16;
    const int nc0  = (wid >> 2) * 64;

    {
        const float4* g = reinterpret_cast<const float4*>(in) + (size_t)r0 * (FDIM/4);
        #pragma unroll
        for (int i = 0; i < 4; ++i) {
            int p = tid + i*TPB;
            int r = p >> 5, c4 = p & 31;
            float4 v = make_float4(0.f,0.f,0.f,0.f);
            if (r0 + r < R) v = g[p];
            ushort4 o;
            o.x = f2bf(v.x); o.y = f2bf(v.y); o.z = f2bf(v.z); o.w = f2bf(v.w);
            *reinterpret_cast<ushort4*>(&Ab[swz(r, c4*4)]) = o;
        }
    }
    __syncthreads();

    f32x4 acc[4];
    #pragma unroll
    for (int n = 0; n < 4; ++n) acc[n] = (f32x4){0.f,0.f,0.f,0.f};
    gemm_g(Ab, W1pk, mr0, nc0, lane, acc);
    #pragma unroll
    for (int n = 0; n < 4; ++n) {
        int col = nc0 + n*16 + (lane & 15);
        float bv = b1[col];
        #pragma unroll
        for (int q = 0; q < 4; ++q)
            Hb[swz(mr0 + (lane >> 4)*4 + q, col)] = f2bf(silu_f(acc[n][q] + bv));
    }
    __syncthreads();

    #pragma unroll
    for (int n = 0; n < 4; ++n) acc[n] = (f32x4){0.f,0.f,0.f,0.f};
    gemm_g(Hb, W2pk, mr0, nc0, lane, acc);
    #pragma unroll
    for (int n = 0; n < 4; ++n) {
        int col = nc0 + n*16 + (lane & 15);
        float bv = b2[col];
        #pragma unroll
        for (int q = 0; q < 4; ++q) {
            int grow = r0 + mr0 + (lane >> 4)*4 + q;
            if (grow < R) out[(size_t)grow*FDIM + col] = acc[n][q] + bv;
        }
    }
}

// ================================================================ fused edge layer
// R13 structure + pk-fma dot + fold-gather software pipeline (T14).
__global__ __launch_bounds__(TPB, 6)
void edge_layer_kernel(const float* __restrict__ sdisp,
                       const int* __restrict__ se0, const int* __restrict__ se1,
                       const float* __restrict__ mnp,
                       const float* __restrict__ meW,
                       const unsigned short* __restrict__ W11pk,
                       const unsigned short* __restrict__ W12pk,
                       const unsigned short* __restrict__ W21pk,
                       const unsigned short* __restrict__ W22pk,
                       const float* __restrict__ fold,
                       float* __restrict__ atom,
                       float* __restrict__ fnew,
                       int E)
{
    __shared__ __align__(16) union {
        struct { unsigned short Ab[CHUNK*FDIM]; unsigned short Hb0[CHUNK*FDIM]; } g;
        float S[CHUNK*FDIM];                    // 32 KB fp32 staging (fnew scatter)
    } U;
    __shared__ __align__(16) union {
        unsigned short Hb1[CHUNK*FDIM];         // 16 KB (written in G3, after de is dead)
        float de[CHUNK][NBASIS];                // 5 KB  (P0/P1 only; 80B rows, 16B-aligned)
    } V;
    __shared__ float dirc[CHUNK][3];
    __shared__ int   e0c[CHUNK], e1c[CHUNK];
    __shared__ int   segrow[CHUNK];
    __shared__ int   nseg_sh;

    const int tid  = threadIdx.x;
    const int lane = tid & 63;
    const int wid  = tid >> 6;
    const int r0   = blockIdx.x * CHUNK;
    const int nvalid = min(CHUNK, E - r0);
    const int mr0  = (wid & 3) * 16;
    const int nc0  = (wid >> 2) * 64;

    // ---- P0: edge embedding (sine recurrence) + segment list (wave 0)
    if (tid < CHUNK) {
        int r = tid;
        int gidx  = r0 + min(r, nvalid - 1);
        int gprev = r0 + min(r - 1, nvalid - 1);
        int e0v = se0[gidx];
        bool head = (r == 0) || (r < nvalid && se0[gprev] != e0v);
        e0c[r] = e0v;
        int a1i = 0;
        float x = 0.f, y = 0.f, zz = 0.f;
        if (r < nvalid) {
            a1i = se1[r0 + r];
            const float* dp = sdisp + 3*(size_t)(r0 + r);
            x = dp[0]; y = dp[1]; zz = dp[2];
        }
        e1c[r] = a1i;
        float d   = sqrtf(x*x + y*y + zz*zz);
        float inv = (r < nvalid) ? 1.0f/d : 0.f;
        dirc[r][0] = x*inv; dirc[r][1] = y*inv; dirc[r][2] = zz*inv;
        float w   = PI_F * d / RCUT;
        float cut = (d < RCUT) ? 0.5f*(cosf(w) + 1.f) : 0.f;
        float coef = sqrtf(2.f/RCUT) * cut * inv;
        float s1 = sinf(w);
        float c2 = 2.f * cosf(w);
        V.de[r][0] = coef * s1;
        float sm2 = 0.f, sm1 = s1;
        #pragma unroll
        for (int nn = 2; nn <= NBASIS; ++nn) {
            float sn = c2*sm1 - sm2;
            V.de[r][nn-1] = coef * sn;
            sm2 = sm1; sm1 = sn;
        }
        unsigned long long mask = __ballot(head);
        int sid = __popcll(mask & ((1ULL << r) - 1ULL));
        if (head) segrow[sid] = r;
        if (r == 0) nseg_sh = (int)__popcll(mask);
    }
    __syncthreads();

    // ---- P1: msg = (de.mew)*mnp[e0]*mnp[e1]; segment-flushed atom scatter; Ab=bf16
    {
        const int f  = tid & 127;
        const int q4 = tid >> 7;                 // rows q4*16 .. +15 (consecutive)
        // issue the 16 random-row gathers first (long latency)
        float m1v[16];
        #pragma unroll
        for (int i = 0; i < 16; ++i)
            m1v[i] = mnp[(size_t)e1c[q4*16 + i]*FDIM + f];
        f32x2 mw[10];
        {
            const f32x2* wr = reinterpret_cast<const f32x2*>(meW + (size_t)f*NBASIS);
            #pragma unroll
            for (int k = 0; k < 10; ++k) mw[k] = wr[k];
        }
        int   prev = e0c[q4*16];
        float mv0  = mnp[(size_t)prev*FDIM + f];
        float macc = 0.f;
        #pragma unroll
        for (int i = 0; i < 16; ++i) {
            int r = q4*16 + i;
            int e0 = e0c[r];
            if (e0 != prev) {
                atomicAdd(&atom[(size_t)prev*FDIM + f], macc);
                macc = 0.f; prev = e0;
                mv0 = mnp[(size_t)e0*FDIM + f];
            }
            float m = 0.f;
            if (r < nvalid) {
                const f32x2* der = reinterpret_cast<const f32x2*>(&V.de[r][0]);
                f32x2 acc2 = (f32x2){0.f, 0.f};
                #pragma unroll
                for (int k = 0; k < 10; ++k)        // v_pk_fma_f32 x10
                    acc2 += der[k] * mw[k];
                float mep = acc2.x + acc2.y;
                m = mep * mv0 * m1v[i];
                macc += m;
            }
            U.g.Ab[swz(r, f)] = f2bf(m);
        }
        atomicAdd(&atom[(size_t)prev*FDIM + f], macc);
    }
    __syncthreads();        // Ab ready; de dead from here

    f32x4 va1[4], va2[4];

    // ---- G1: Hb0 = silu(msg @ W11^T);  G3: Hb1 = silu(msg @ W21^T)
    #pragma unroll
    for (int n = 0; n < 4; ++n) va1[n] = (f32x4){0.f,0.f,0.f,0.f};
    gemm_g(U.g.Ab, W11pk, mr0, nc0, lane, va1);
    #pragma unroll
    for (int n = 0; n < 4; ++n)
        #pragma unroll
        for (int q = 0; q < 4; ++q)
            U.g.Hb0[swz(mr0 + (lane >> 4)*4 + q, nc0 + n*16 + (lane & 15))] =
                f2bf(silu_f(va1[n][q]));

    #pragma unroll
    for (int n = 0; n < 4; ++n) va2[n] = (f32x4){0.f,0.f,0.f,0.f};
    gemm_g(U.g.Ab, W21pk, mr0, nc0, lane, va2);
    #pragma unroll
    for (int n = 0; n < 4; ++n)
        #pragma unroll
        for (int q = 0; q < 4; ++q)
            V.Hb1[swz(mr0 + (lane >> 4)*4 + q, nc0 + n*16 + (lane & 15))] =
                f2bf(silu_f(va2[n][q]));
    __syncthreads();        // Hb0, Hb1 complete (cross-wave)

    // per-thread fold row bases (4 rows), used by the pipelined gathers
    const float* fbase[4];
    #pragma unroll
    for (int q = 0; q < 4; ++q)
        fbase[q] = fold + (size_t)e1c[mr0 + (lane >> 4)*4 + q]*3*FDIM + (lane & 15);

    // prefetch v=0 fold values (latency hides under G2/G4 MFMAs below)
    float fv_cur[16];
    #pragma unroll
    for (int q = 0; q < 4; ++q)
        #pragma unroll
        for (int n = 0; n < 4; ++n)
            fv_cur[q*4+n] = fbase[q][0*FDIM + nc0 + n*16];

    // ---- G2: va1 = h1 @ W12^T;  G4: va2 = h2 @ W22^T
    #pragma unroll
    for (int n = 0; n < 4; ++n) va1[n] = (f32x4){0.f,0.f,0.f,0.f};
    gemm_g(U.g.Hb0, W12pk, mr0, nc0, lane, va1);
    #pragma unroll
    for (int n = 0; n < 4; ++n) va2[n] = (f32x4){0.f,0.f,0.f,0.f};
    gemm_g(V.Hb1, W22pk, mr0, nc0, lane, va2);
    __syncthreads();        // all Ab/Hb reads done -> U.S may overwrite

    // ---- scatter: fnew[e0] += a1*dir + a2*fold[e1], segment-reduced per v
    // fold gathers pipelined one v ahead (issue after stage, consume after reduce).
    const int nseg = nseg_sh;
    #pragma unroll
    for (int v = 0; v < 3; ++v) {
        #pragma unroll
        for (int q = 0; q < 4; ++q) {
            int row = mr0 + (lane >> 4)*4 + q;
            float dv = dirc[row][v];
            #pragma unroll
            for (int n = 0; n < 4; ++n) {
                int col = nc0 + n*16 + (lane & 15);
                U.S[swz4(row, col)] = va1[n][q]*dv + va2[n][q]*fv_cur[q*4+n];
            }
        }
        float fv_nxt[16];
        if (v < 2) {
            #pragma unroll
            for (int q = 0; q < 4; ++q)
                #pragma unroll
                for (int n = 0; n < 4; ++n)
                    fv_nxt[q*4+n] = fbase[q][(v+1)*FDIM + nc0 + n*16];
        }
        __syncthreads();
        {
            int col = tid & 127;
            for (int s = tid >> 7; s < nseg; s += 4) {
                int rb = segrow[s];
                int re = (s + 1 < nseg) ? segrow[s+1] : CHUNK;
                float sum = 0.f;
                for (int r = rb; r < re; ++r) sum += U.S[swz4(r, col)];
                atomicAdd(&fnew[(size_t)e0c[rb]*3*FDIM + v*FDIM + col], sum);
            }
        }
        __syncthreads();
        #pragma unroll
        for (int i = 0; i < 16; ++i) fv_cur[i] = fv_nxt[i];
    }
}

// ================================================================ node update (MFMA, global B)
// Also streams a copy of fc into fcopy (next layer's fnew base).
__global__ __launch_bounds__(TPB, 6)
void upd_mfma_kernel(const float* __restrict__ fc, const unsigned short* __restrict__ Wpk,
                     float* __restrict__ atom, float* __restrict__ fcopy, int R)
{
    __shared__ __align__(16) unsigned short Ab[CHUNK*FDIM];
    const int tid  = threadIdx.x;
    const int lane = tid & 63;
    const int wid  = tid >> 6;
    const int r0   = blockIdx.x * CHUNK;
    const int mr0  = (wid & 3) * 16;
    const int nc0  = (wid >> 2) * 64;

    {
        const float4* g = reinterpret_cast<const float4*>(fc) + (size_t)r0 * (FDIM/4);
        float4*      cp = fcopy ? reinterpret_cast<float4*>(fcopy) + (size_t)r0 * (FDIM/4)
                                : nullptr;
        #pragma unroll
        for (int i = 0; i < 4; ++i) {
            int p = tid + i*TPB;
            int r = p >> 5, c4 = p & 31;
            float4 v = make_float4(0.f,0.f,0.f,0.f);
            if (r0 + r < R) {
                v = g[p];
                if (cp) cp[p] = v;
            }
            ushort4 o;
            o.x = f2bf(v.x); o.y = f2bf(v.y); o.z = f2bf(v.z); o.w = f2bf(v.w);
            *reinterpret_cast<ushort4*>(&Ab[swz(r, c4*4)]) = o;
        }
    }
    __syncthreads();

    f32x4 acc[4];
    #pragma unroll
    for (int n = 0; n < 4; ++n) acc[n] = (f32x4){0.f,0.f,0.f,0.f};
    gemm_g(Ab, Wpk, mr0, nc0, lane, acc);

    #pragma unroll
    for (int n = 0; n < 4; ++n)
        #pragma unroll
        for (int q = 0; q < 4; ++q) {
            int row  = mr0 + (lane >> 4)*4 + q;
            int col  = nc0 + n*16 + (lane & 15);
            int grow = r0 + row;
            if (grow < R) {
                float fv = fc[(size_t)grow*FDIM + col];
                atomicAdd(&atom[(size_t)(grow/3)*FDIM + col], acc[n][q] * fv);
            }
        }
}

// ---------------------------------------------------------------- launch
extern "C" void kernel_launch(void* const* d_in, const int* in_sizes, int n_in,
                              void* d_out, int out_size, void* d_ws, size_t ws_size,
                              hipStream_t stream)
{
    const int*   zc    = (const int*)d_in[0];
    const float* disp  = (const float*)d_in[1];
    const int*   ei    = (const int*)d_in[2];
    const float* emb   = (const float*)d_in[4];
    const float* mnpW1 = (const float*)d_in[5];
    const float* mnpb1 = (const float*)d_in[6];
    const float* mnpW2 = (const float*)d_in[7];
    const float* mnpb2 = (const float*)d_in[8];
    const float* meW   = (const float*)d_in[9];
    const float* eq1W1 = (const float*)d_in[10];
    const float* eq1W2 = (const float*)d_in[11];
    const float* eq2W1 = (const float*)d_in[12];
    const float* eq2W2 = (const float*)d_in[13];
    const float* updW  = (const float*)d_in[14];

    const int N = in_sizes[0];
    const int E = in_sizes[1] / 3;
    const int* ei0 = ei;
    const int* ei1 = ei + E;

    float* atom = (float*)d_out;                      // [N,F]
    float* fB   = (float*)d_out + (size_t)N * FDIM;   // [N,3,F] (final force)

    float* ws   = (float*)d_ws;
    float* mnp   = ws;  ws += (size_t)N * FDIM;
    float* fA    = ws;  ws += (size_t)N * 3 * FDIM;
    float* sdisp = ws;  ws += (size_t)E * 3;
    unsigned short* wpk = (unsigned short*)ws;        // 21 x 128x128 bf16 packed
    ws = (float*)(wpk + (size_t)21 * FDIM * FDIM);
    int*   hist  = (int*)ws;
    int*   off   = hist + N;
    int*   se0   = off + N + 1;
    int*   se1   = se0 + E;

    const int n4F3 = N * 3 * FDIM / 4;
    const int eb   = (E + 255) / 256;
    const size_t MS = (size_t)FDIM * FDIM;            // ushorts per packed 128x128

    // one-time: pack weights + sort edges by destination
    pack_w_kernel<<<(21*2048 + 255)/256, 256, 0, stream>>>(
        mnpW1, mnpW2, eq1W1, eq1W2, eq2W1, eq2W2, updW, wpk);
    hipMemsetAsync(hist, 0, (size_t)N * sizeof(int), stream);
    hist_kernel<<<eb, 256, 0, stream>>>(ei0, hist, E);
    prefix_kernel<<<1, 1024, 0, stream>>>(hist, off, N, E);
    scatter_kernel<<<eb, 256, 0, stream>>>(ei0, ei1, disp, off, se0, se1, sdisp, E);

    atom_init_kernel<<<(N*FDIM + 255)/256, 256, 0, stream>>>(zc, emb, atom, N);
    zero4_kernel<<<(n4F3 + 255)/256, 256, 0, stream>>>((float4*)fA, n4F3);

    for (int l = 0; l < NLAYERS; ++l) {
        const float* fold;  float* fnew;
        if      (l == 0) { fold = fA; fnew = fB; }
        else if (l == 1) { fold = fB; fnew = fA; }
        else             { fold = fA; fnew = fB; }

        const unsigned short* Lpk = wpk + (size_t)l * 7 * MS;

        node_mlp_g_kernel<<<(N + CHUNK - 1)/CHUNK, TPB, 0, stream>>>(
            atom, mnp,
            Lpk + 0*MS, mnpb1 + (size_t)l*FDIM,
            Lpk + 1*MS, mnpb2 + (size_t)l*FDIM, N);

        if (l == 0) zero4_kernel<<<(n4F3 + 255)/256, 256, 0, stream>>>((float4*)fnew, n4F3);

        edge_layer_kernel<<<(E + CHUNK - 1)/CHUNK, TPB, 0, stream>>>(
            sdisp, se0, se1, mnp,
            meW + (size_t)l*FDIM*NBASIS,
            Lpk + 2*MS, Lpk + 3*MS, Lpk + 4*MS, Lpk + 5*MS,
            fold, atom, fnew, E);

        // upd also streams fnew into the buffer that becomes next layer's fnew
        upd_mfma_kernel<<<(3*N + CHUNK - 1)/CHUNK, TPB, 0, stream>>>(
            fnew, Lpk + 6*MS, atom,
            (l < NLAYERS-1) ? (float*)fold : nullptr, 3*N);
    }
}

// Round 15
// 774.940 us; speedup vs baseline: 1.0160x; 1.0160x over previous
//
#include <hip/hip_runtime.h>
#include <hip/hip_bf16.h>
#include <cstdint>
#include <cstddef>

#define FDIM   128
#define NBASIS 20
#define NLAYERS 3
#define RCUT   5.0f
#define PI_F   3.14159265358979323846f
#define CHUNK  64
#define TPB    512

typedef __attribute__((ext_vector_type(8))) short bf16x8;
typedef __attribute__((ext_vector_type(4))) float f32x4;

// 1-ulp rcp is fine: result is rounded to bf16 downstream.
__device__ __forceinline__ float silu_f(float x) {
    return x * __builtin_amdgcn_rcpf(1.f + __expf(-x));
}

__device__ __forceinline__ unsigned short f2bf(float x) {
    __hip_bfloat16 h = __float2bfloat16(x);
    unsigned short u;
    __builtin_memcpy(&u, &h, 2);
    return u;
}

// swizzled element index for bf16 LDS tiles with 128-elem rows
__device__ __forceinline__ int swz(int row, int col) {
    return row * FDIM + (col ^ ((row & 7) << 3));
}
// fp32 staging swizzle (4-elem granules)
__device__ __forceinline__ int swz4(int row, int col) {
    return row * FDIM + (col ^ ((row & 7) << 2));
}

// ---------------------------------------------------------------- small utility kernels
__global__ __launch_bounds__(256)
void atom_init_kernel(const int* __restrict__ zc, const float* __restrict__ emb,
                      float* __restrict__ atom, int N)
{
    int t = blockIdx.x * 256 + threadIdx.x;
    if (t >= N * FDIM) return;
    int n = t >> 7, f = t & 127;
    atom[t] = emb[zc[n]*FDIM + f];
}

__global__ __launch_bounds__(256)
void zero4_kernel(float4* __restrict__ p, int n4)
{
    int t = blockIdx.x * 256 + threadIdx.x;
    if (t < n4) p[t] = make_float4(0.f,0.f,0.f,0.f);
}

// ---------------------------------------------------------------- weight pre-pack
// Fragment order: Wpk[m][((r16*4+ks)*64 + lane)*8 + j]
//   = bf16( W[r16*16 + (lane&15)][ks*32 + (lane>>4)*8 + j] )
__global__ __launch_bounds__(256)
void pack_w_kernel(const float* __restrict__ mnpW1, const float* __restrict__ mnpW2,
                   const float* __restrict__ e11,   const float* __restrict__ e12,
                   const float* __restrict__ e21,   const float* __restrict__ e22,
                   const float* __restrict__ updW,
                   unsigned short* __restrict__ wpk)
{
    int t = blockIdx.x * 256 + threadIdx.x;
    if (t >= 21 * 2048) return;
    int m = t >> 11, p = t & 2047;
    int layer = m / 7, kind = m % 7;
    const float* base;
    switch (kind) {
        case 0: base = mnpW1; break;
        case 1: base = mnpW2; break;
        case 2: base = e11;   break;
        case 3: base = e12;   break;
        case 4: base = e21;   break;
        case 5: base = e22;   break;
        default: base = updW; break;
    }
    base += (size_t)layer * FDIM * FDIM;
    int l   = p & 63, fr = p >> 6;
    int r16 = fr >> 2, ks = fr & 3;
    int row = r16*16 + (l & 15);
    int col = ks*32 + (l >> 4)*8;
    const float* src = base + (size_t)row*FDIM + col;
    float4 v0 = *reinterpret_cast<const float4*>(src);
    float4 v1 = *reinterpret_cast<const float4*>(src + 4);
    unsigned short* dst = wpk + (size_t)t * 8;
    ushort4 o0, o1;
    o0.x = f2bf(v0.x); o0.y = f2bf(v0.y); o0.z = f2bf(v0.z); o0.w = f2bf(v0.w);
    o1.x = f2bf(v1.x); o1.y = f2bf(v1.y); o1.z = f2bf(v1.z); o1.w = f2bf(v1.w);
    *reinterpret_cast<ushort4*>(dst)     = o0;
    *reinterpret_cast<ushort4*>(dst + 4) = o1;
}

// ---------------------------------------------------------------- edge sort (by ei0)
__global__ __launch_bounds__(256)
void hist_kernel(const int* __restrict__ ei0, int* __restrict__ hist, int E)
{
    int e = blockIdx.x * 256 + threadIdx.x;
    if (e < E) atomicAdd(&hist[ei0[e]], 1);
}

__global__ __launch_bounds__(1024)
void prefix_kernel(const int* __restrict__ hist, int* __restrict__ off, int N, int E)
{
    __shared__ int buf[1024];
    __shared__ int carry;
    const int tid = threadIdx.x;
    if (tid == 0) carry = 0;
    __syncthreads();
    for (int base = 0; base < N; base += 1024) {
        int i = base + tid;
        int v = (i < N) ? hist[i] : 0;
        buf[tid] = v;
        __syncthreads();
        for (int d = 1; d < 1024; d <<= 1) {
            int t = (tid >= d) ? buf[tid - d] : 0;
            __syncthreads();
            buf[tid] += t;
            __syncthreads();
        }
        if (i < N) off[i] = carry + buf[tid] - v;   // exclusive
        __syncthreads();
        if (tid == 0) carry += buf[1023];
        __syncthreads();
    }
}

__global__ __launch_bounds__(256)
void scatter_kernel(const int* __restrict__ ei0, const int* __restrict__ ei1,
                    const float* __restrict__ disp, int* __restrict__ off,
                    int* __restrict__ se0, int* __restrict__ se1,
                    float* __restrict__ sdisp, int E)
{
    int e = blockIdx.x * 256 + threadIdx.x;
    if (e >= E) return;
    int n = ei0[e];
    int pos = atomicAdd(&off[n], 1);
    se0[pos] = n;
    se1[pos] = ei1[e];
    sdisp[3*pos+0] = disp[3*e+0];
    sdisp[3*pos+1] = disp[3*e+1];
    sdisp[3*pos+2] = disp[3*e+2];
}

// ================================================================ gemm: A from LDS, B from packed global
__device__ __forceinline__ void gemm_g(const unsigned short* __restrict__ Ab,
                                       const unsigned short* __restrict__ Bpk,
                                       int mr0, int nc0, int lane, f32x4 acc[4])
{
    #pragma unroll
    for (int ks = 0; ks < 4; ++ks) {
        bf16x8 a = *reinterpret_cast<const bf16x8*>(
            &Ab[swz(mr0 + (lane & 15), ks*32 + (lane >> 4)*8)]);
        #pragma unroll
        for (int n = 0; n < 4; ++n) {
            int r16 = (nc0 >> 4) + n;
            bf16x8 b = *reinterpret_cast<const bf16x8*>(
                &Bpk[(size_t)(((r16*4 + ks)*64 + lane)) * 8]);
            acc[n] = __builtin_amdgcn_mfma_f32_16x16x32_bf16(a, b, acc[n], 0, 0, 0);
        }
    }
}

// ================================================================ node MLP (bf16 MFMA, global B)
__global__ __launch_bounds__(TPB, 6)
void node_mlp_g_kernel(const float* __restrict__ in, float* __restrict__ out,
                       const unsigned short* __restrict__ W1pk, const float* __restrict__ b1,
                       const unsigned short* __restrict__ W2pk, const float* __restrict__ b2,
                       int R)
{
    __shared__ __align__(16) unsigned short Ab[CHUNK*FDIM];
    __shared__ __align__(16) unsigned short Hb[CHUNK*FDIM];
    const int tid  = threadIdx.x;
    const int lane = tid & 63;
    const int wid  = tid >> 6;
    const int r0   = blockIdx.x * CHUNK;
    const int mr0  = (wid & 3) * 16;
    const int nc0  = (wid >> 2) * 64;

    {
        const float4* g = reinterpret_cast<const float4*>(in) + (size_t)r0 * (FDIM/4);
        #pragma unroll
        for (int i = 0; i < 4; ++i) {
            int p = tid + i*TPB;
            int r = p >> 5, c4 = p & 31;
            float4 v = make_float4(0.f,0.f,0.f,0.f);
            if (r0 + r < R) v = g[p];
            ushort4 o;
            o.x = f2bf(v.x); o.y = f2bf(v.y); o.z = f2bf(v.z); o.w = f2bf(v.w);
            *reinterpret_cast<ushort4*>(&Ab[swz(r, c4*4)]) = o;
        }
    }
    __syncthreads();

    f32x4 acc[4];
    #pragma unroll
    for (int n = 0; n < 4; ++n) acc[n] = (f32x4){0.f,0.f,0.f,0.f};
    gemm_g(Ab, W1pk, mr0, nc0, lane, acc);
    #pragma unroll
    for (int n = 0; n < 4; ++n) {
        int col = nc0 + n*16 + (lane & 15);
        float bv = b1[col];
        #pragma unroll
        for (int q = 0; q < 4; ++q)
            Hb[swz(mr0 + (lane >> 4)*4 + q, col)] = f2bf(silu_f(acc[n][q] + bv));
    }
    __syncthreads();

    #pragma unroll
    for (int n = 0; n < 4; ++n) acc[n] = (f32x4){0.f,0.f,0.f,0.f};
    gemm_g(Hb, W2pk, mr0, nc0, lane, acc);
    #pragma unroll
    for (int n = 0; n < 4; ++n) {
        int col = nc0 + n*16 + (lane & 15);
        float bv = b2[col];
        #pragma unroll
        for (int q = 0; q < 4; ++q) {
            int grow = r0 + mr0 + (lane >> 4)*4 + q;
            if (grow < R) out[(size_t)grow*FDIM + col] = acc[n][q] + bv;
        }
    }
}

// ================================================================ fused edge layer
// R13-best: {G1,G3} -> one barrier -> {G2,G4} -> barrier -> scatter.
// Vectorized de dot (float4, 80B rows are 16B-aligned) + rcp-silu.
__global__ __launch_bounds__(TPB, 6)
void edge_layer_kernel(const float* __restrict__ sdisp,
                       const int* __restrict__ se0, const int* __restrict__ se1,
                       const float* __restrict__ mnp,
                       const float* __restrict__ meW,
                       const unsigned short* __restrict__ W11pk,
                       const unsigned short* __restrict__ W12pk,
                       const unsigned short* __restrict__ W21pk,
                       const unsigned short* __restrict__ W22pk,
                       const float* __restrict__ fold,
                       float* __restrict__ atom,
                       float* __restrict__ fnew,
                       int E)
{
    __shared__ __align__(16) union {
        struct { unsigned short Ab[CHUNK*FDIM]; unsigned short Hb0[CHUNK*FDIM]; } g;
        float S[CHUNK*FDIM];                    // 32 KB fp32 staging (fnew scatter)
    } U;
    __shared__ __align__(16) union {
        unsigned short Hb1[CHUNK*FDIM];         // 16 KB (written in G3, after de is dead)
        float de[CHUNK][NBASIS];                // 5 KB  (P0/P1 only; 80B rows, 16B-aligned)
    } V;
    __shared__ float dirc[CHUNK][3];
    __shared__ int   e0c[CHUNK], e1c[CHUNK];
    __shared__ int   segrow[CHUNK];
    __shared__ int   nseg_sh;

    const int tid  = threadIdx.x;
    const int lane = tid & 63;
    const int wid  = tid >> 6;
    const int r0   = blockIdx.x * CHUNK;
    const int nvalid = min(CHUNK, E - r0);
    const int mr0  = (wid & 3) * 16;
    const int nc0  = (wid >> 2) * 64;

    // ---- P0: edge embedding (sine recurrence) + segment list (wave 0)
    if (tid < CHUNK) {
        int r = tid;
        int gidx  = r0 + min(r, nvalid - 1);
        int gprev = r0 + min(r - 1, nvalid - 1);
        int e0v = se0[gidx];
        bool head = (r == 0) || (r < nvalid && se0[gprev] != e0v);
        e0c[r] = e0v;
        int a1i = 0;
        float x = 0.f, y = 0.f, zz = 0.f;
        if (r < nvalid) {
            a1i = se1[r0 + r];
            const float* dp = sdisp + 3*(size_t)(r0 + r);
            x = dp[0]; y = dp[1]; zz = dp[2];
        }
        e1c[r] = a1i;
        float d   = sqrtf(x*x + y*y + zz*zz);
        float inv = (r < nvalid) ? 1.0f/d : 0.f;
        dirc[r][0] = x*inv; dirc[r][1] = y*inv; dirc[r][2] = zz*inv;
        float w   = PI_F * d / RCUT;
        float cut = (d < RCUT) ? 0.5f*(cosf(w) + 1.f) : 0.f;
        float coef = sqrtf(2.f/RCUT) * cut * inv;
        float s1 = sinf(w);
        float c2 = 2.f * cosf(w);
        V.de[r][0] = coef * s1;
        float sm2 = 0.f, sm1 = s1;
        #pragma unroll
        for (int nn = 2; nn <= NBASIS; ++nn) {
            float sn = c2*sm1 - sm2;
            V.de[r][nn-1] = coef * sn;
            sm2 = sm1; sm1 = sn;
        }
        unsigned long long mask = __ballot(head);
        int sid = __popcll(mask & ((1ULL << r) - 1ULL));
        if (head) segrow[sid] = r;
        if (r == 0) nseg_sh = (int)__popcll(mask);
    }
    __syncthreads();

    // ---- P1: msg = (de.mew)*mnp[e0]*mnp[e1]; segment-flushed atom scatter; Ab=bf16
    {
        const int f  = tid & 127;
        const int q4 = tid >> 7;                 // rows q4*16 .. +15 (consecutive)
        // issue the 16 random-row gathers first (long latency)
        float m1v[16];
        #pragma unroll
        for (int i = 0; i < 16; ++i)
            m1v[i] = mnp[(size_t)e1c[q4*16 + i]*FDIM + f];
        float4 mw[5];
        {
            const float* wr = meW + (size_t)f*NBASIS;
            #pragma unroll
            for (int k = 0; k < 5; ++k)
                mw[k] = *reinterpret_cast<const float4*>(wr + 4*k);
        }
        int   prev = e0c[q4*16];
        float mv0  = mnp[(size_t)prev*FDIM + f];
        float macc = 0.f;
        #pragma unroll
        for (int i = 0; i < 16; ++i) {
            int r = q4*16 + i;
            int e0 = e0c[r];
            if (e0 != prev) {
                atomicAdd(&atom[(size_t)prev*FDIM + f], macc);
                macc = 0.f; prev = e0;
                mv0 = mnp[(size_t)e0*FDIM + f];
            }
            float m = 0.f;
            if (r < nvalid) {
                const float4* der = reinterpret_cast<const float4*>(&V.de[r][0]);
                float mep = 0.f;
                #pragma unroll
                for (int k = 0; k < 5; ++k) {          // 5x ds_read_b128 (wave-uniform)
                    float4 d = der[k];
                    mep += d.x*mw[k].x + d.y*mw[k].y + d.z*mw[k].z + d.w*mw[k].w;
                }
                m = mep * mv0 * m1v[i];
                macc += m;
            }
            U.g.Ab[swz(r, f)] = f2bf(m);
        }
        atomicAdd(&atom[(size_t)prev*FDIM + f], macc);
    }
    __syncthreads();        // Ab ready; de dead from here

    f32x4 va1[4], va2[4];

    // ---- G1: Hb0 = silu(msg @ W11^T);  G3: Hb1 = silu(msg @ W21^T)
    #pragma unroll
    for (int n = 0; n < 4; ++n) va1[n] = (f32x4){0.f,0.f,0.f,0.f};
    gemm_g(U.g.Ab, W11pk, mr0, nc0, lane, va1);
    #pragma unroll
    for (int n = 0; n < 4; ++n)
        #pragma unroll
        for (int q = 0; q < 4; ++q)
            U.g.Hb0[swz(mr0 + (lane >> 4)*4 + q, nc0 + n*16 + (lane & 15))] =
                f2bf(silu_f(va1[n][q]));

    #pragma unroll
    for (int n = 0; n < 4; ++n) va2[n] = (f32x4){0.f,0.f,0.f,0.f};
    gemm_g(U.g.Ab, W21pk, mr0, nc0, lane, va2);
    #pragma unroll
    for (int n = 0; n < 4; ++n)
        #pragma unroll
        for (int q = 0; q < 4; ++q)
            V.Hb1[swz(mr0 + (lane >> 4)*4 + q, nc0 + n*16 + (lane & 15))] =
                f2bf(silu_f(va2[n][q]));
    __syncthreads();        // Hb0, Hb1 complete (cross-wave)

    // ---- G2: va1 = h1 @ W12^T;  G4: va2 = h2 @ W22^T
    #pragma unroll
    for (int n = 0; n < 4; ++n) va1[n] = (f32x4){0.f,0.f,0.f,0.f};
    gemm_g(U.g.Hb0, W12pk, mr0, nc0, lane, va1);
    #pragma unroll
    for (int n = 0; n < 4; ++n) va2[n] = (f32x4){0.f,0.f,0.f,0.f};
    gemm_g(V.Hb1, W22pk, mr0, nc0, lane, va2);
    __syncthreads();        // all Ab/Hb reads done -> U.S may overwrite

    // ---- scatter: fnew[e0] += a1*dir + a2*fold[e1], segment-reduced per v
    const int nseg = nseg_sh;
    for (int v = 0; v < 3; ++v) {
        #pragma unroll
        for (int q = 0; q < 4; ++q) {
            int row = mr0 + (lane >> 4)*4 + q;
            const float* fb = fold + (size_t)e1c[row]*3*FDIM + v*FDIM;
            float dv = dirc[row][v];
            #pragma unroll
            for (int n = 0; n < 4; ++n) {
                int col = nc0 + n*16 + (lane & 15);
                U.S[swz4(row, col)] = va1[n][q]*dv + va2[n][q]*fb[col];
            }
        }
        __syncthreads();
        {
            int col = tid & 127;
            for (int s = tid >> 7; s < nseg; s += 4) {
                int rb = segrow[s];
                int re = (s + 1 < nseg) ? segrow[s+1] : CHUNK;
                float sum = 0.f;
                for (int r = rb; r < re; ++r) sum += U.S[swz4(r, col)];
                atomicAdd(&fnew[(size_t)e0c[rb]*3*FDIM + v*FDIM + col], sum);
            }
        }
        __syncthreads();
    }
}

// ================================================================ node update (MFMA, global B)
// Also streams a copy of fc into fcopy (next layer's fnew base).
__global__ __launch_bounds__(TPB, 6)
void upd_mfma_kernel(const float* __restrict__ fc, const unsigned short* __restrict__ Wpk,
                     float* __restrict__ atom, float* __restrict__ fcopy, int R)
{
    __shared__ __align__(16) unsigned short Ab[CHUNK*FDIM];
    const int tid  = threadIdx.x;
    const int lane = tid & 63;
    const int wid  = tid >> 6;
    const int r0   = blockIdx.x * CHUNK;
    const int mr0  = (wid & 3) * 16;
    const int nc0  = (wid >> 2) * 64;

    {
        const float4* g = reinterpret_cast<const float4*>(fc) + (size_t)r0 * (FDIM/4);
        float4*      cp = fcopy ? reinterpret_cast<float4*>(fcopy) + (size_t)r0 * (FDIM/4)
                                : nullptr;
        #pragma unroll
        for (int i = 0; i < 4; ++i) {
            int p = tid + i*TPB;
            int r = p >> 5, c4 = p & 31;
            float4 v = make_float4(0.f,0.f,0.f,0.f);
            if (r0 + r < R) {
                v = g[p];
                if (cp) cp[p] = v;
            }
            ushort4 o;
            o.x = f2bf(v.x); o.y = f2bf(v.y); o.z = f2bf(v.z); o.w = f2bf(v.w);
            *reinterpret_cast<ushort4*>(&Ab[swz(r, c4*4)]) = o;
        }
    }
    __syncthreads();

    f32x4 acc[4];
    #pragma unroll
    for (int n = 0; n < 4; ++n) acc[n] = (f32x4){0.f,0.f,0.f,0.f};
    gemm_g(Ab, Wpk, mr0, nc0, lane, acc);

    #pragma unroll
    for (int n = 0; n < 4; ++n)
        #pragma unroll
        for (int q = 0; q < 4; ++q) {
            int row  = mr0 + (lane >> 4)*4 + q;
            int col  = nc0 + n*16 + (lane & 15);
            int grow = r0 + row;
            if (grow < R) {
                float fv = fc[(size_t)grow*FDIM + col];
                atomicAdd(&atom[(size_t)(grow/3)*FDIM + col], acc[n][q] * fv);
            }
        }
}

// ---------------------------------------------------------------- launch
extern "C" void kernel_launch(void* const* d_in, const int* in_sizes, int n_in,
                              void* d_out, int out_size, void* d_ws, size_t ws_size,
                              hipStream_t stream)
{
    const int*   zc    = (const int*)d_in[0];
    const float* disp  = (const float*)d_in[1];
    const int*   ei    = (const int*)d_in[2];
    const float* emb   = (const float*)d_in[4];
    const float* mnpW1 = (const float*)d_in[5];
    const float* mnpb1 = (const float*)d_in[6];
    const float* mnpW2 = (const float*)d_in[7];
    const float* mnpb2 = (const float*)d_in[8];
    const float* meW   = (const float*)d_in[9];
    const float* eq1W1 = (const float*)d_in[10];
    const float* eq1W2 = (const float*)d_in[11];
    const float* eq2W1 = (const float*)d_in[12];
    const float* eq2W2 = (const float*)d_in[13];
    const float* updW  = (const float*)d_in[14];

    const int N = in_sizes[0];
    const int E = in_sizes[1] / 3;
    const int* ei0 = ei;
    const int* ei1 = ei + E;

    float* atom = (float*)d_out;                      // [N,F]
    float* fB   = (float*)d_out + (size_t)N * FDIM;   // [N,3,F] (final force)

    float* ws   = (float*)d_ws;
    float* mnp   = ws;  ws += (size_t)N * FDIM;
    float* fA    = ws;  ws += (size_t)N * 3 * FDIM;
    float* sdisp = ws;  ws += (size_t)E * 3;
    unsigned short* wpk = (unsigned short*)ws;        // 21 x 128x128 bf16 packed
    ws = (float*)(wpk + (size_t)21 * FDIM * FDIM);
    int*   hist  = (int*)ws;
    int*   off   = hist + N;
    int*   se0   = off + N + 1;
    int*   se1   = se0 + E;

    const int n4F3 = N * 3 * FDIM / 4;
    const int eb   = (E + 255) / 256;
    const size_t MS = (size_t)FDIM * FDIM;            // ushorts per packed 128x128

    // one-time: pack weights + sort edges by destination
    pack_w_kernel<<<(21*2048 + 255)/256, 256, 0, stream>>>(
        mnpW1, mnpW2, eq1W1, eq1W2, eq2W1, eq2W2, updW, wpk);
    hipMemsetAsync(hist, 0, (size_t)N * sizeof(int), stream);
    hist_kernel<<<eb, 256, 0, stream>>>(ei0, hist, E);
    prefix_kernel<<<1, 1024, 0, stream>>>(hist, off, N, E);
    scatter_kernel<<<eb, 256, 0, stream>>>(ei0, ei1, disp, off, se0, se1, sdisp, E);

    atom_init_kernel<<<(N*FDIM + 255)/256, 256, 0, stream>>>(zc, emb, atom, N);
    zero4_kernel<<<(n4F3 + 255)/256, 256, 0, stream>>>((float4*)fA, n4F3);

    for (int l = 0; l < NLAYERS; ++l) {
        const float* fold;  float* fnew;
        if      (l == 0) { fold = fA; fnew = fB; }
        else if (l == 1) { fold = fB; fnew = fA; }
        else             { fold = fA; fnew = fB; }

        const unsigned short* Lpk = wpk + (size_t)l * 7 * MS;

        node_mlp_g_kernel<<<(N + CHUNK - 1)/CHUNK, TPB, 0, stream>>>(
            atom, mnp,
            Lpk + 0*MS, mnpb1 + (size_t)l*FDIM,
            Lpk + 1*MS, mnpb2 + (size_t)l*FDIM, N);

        if (l == 0) zero4_kernel<<<(n4F3 + 255)/256, 256, 0, stream>>>((float4*)fnew, n4F3);

        edge_layer_kernel<<<(E + CHUNK - 1)/CHUNK, TPB, 0, stream>>>(
            sdisp, se0, se1, mnp,
            meW + (size_t)l*FDIM*NBASIS,
            Lpk + 2*MS, Lpk + 3*MS, Lpk + 4*MS, Lpk + 5*MS,
            fold, atom, fnew, E);

        // upd also streams fnew into the buffer that becomes next layer's fnew
        upd_mfma_kernel<<<(3*N + CHUNK - 1)/CHUNK, TPB, 0, stream>>>(
            fnew, Lpk + 6*MS, atom,
            (l < NLAYERS-1) ? (float*)fold : nullptr, 3*N);
    }
}